// Round 13
// baseline (287.089 us; speedup 1.0000x reference)
//
#include <hip/hip_runtime.h>
#include <hip/hip_bf16.h>
#include <hip/hip_fp16.h>

// BinaryTreeLSTM  B=64, L=1024, IN_DIM=300, MEM=256 — v13.
// 12 launches: prep -> leaf -> L512 -> ... -> L2 -> L1(final).
// ALL tree levels via the proven mfma_gemm (v10 core, 2-buffer, 4 blocks/CU,
// conflict-free both-sides swizzle, fp16 c-state). The per-batch monolithic
// tail was single-CU L2-BW-walled (1MB weights/level/block ≈ 8us/level);
// col/row-split launches spread the weight stream across CUs instead.
// MODE 0 = leaf, 1 = level (c fp16 + h bf16), 2 = final (fp32 c,h -> dout).

typedef __attribute__((ext_vector_type(8))) short bf16x8;
typedef __attribute__((ext_vector_type(4))) float f32x4;

__device__ __forceinline__ float fsig(float x)  { return 1.f / (1.f + __expf(-x)); }
__device__ __forceinline__ float ftanh(float x) { return 1.f - 2.f / (__expf(2.f * x) + 1.f); }
__device__ __forceinline__ ushort f2bf(float x) {
    __hip_bfloat16 b = __float2bfloat16(x);
    return *reinterpret_cast<ushort*>(&b);
}

__device__ __forceinline__ void gld_lds16(const void* g, void* l) {
    __builtin_amdgcn_global_load_lds((const __attribute__((address_space(1))) void*)g,
                                     (__attribute__((address_space(3))) void*)l, 16, 0, 0);
}

// ---------------- prep: pack level + pack leaf + biases + embs->bf16 ----------------
__global__ void prep(const float* __restrict__ Wl,  const float* __restrict__ Wr,
                     const float* __restrict__ bl,  const float* __restrict__ br,
                     const float* __restrict__ Wcx, const float* __restrict__ Wox,
                     const float* __restrict__ bcx, const float* __restrict__ box,
                     const float* __restrict__ embs,
                     ushort* __restrict__ Wb2, ushort* __restrict__ WbL,
                     float* __restrict__ bp2, float* __restrict__ bpL,
                     ushort* __restrict__ embsB)
{
    const int gid = blockIdx.x * 256 + threadIdx.x;     // 1024 blocks -> 262144
    for (int i = gid; i < 524288; i += 262144) {
        int e = i & 7, slot = (i >> 3) & 3, o = (i >> 5) & 255;
        int g = (i >> 13) & 3, t = i >> 15;
        int q = slot ^ ((o >> 1) & 3);
        int k = t * 32 + q * 8 + e;
        float v = (k < 256) ? Wl[(g * 256 + o) * 256 + k]
                            : Wr[(g * 256 + o) * 256 + (k - 256)];
        Wb2[i] = f2bf(v);
    }
    if (gid < 163840) {
        int e = gid & 7, slot = (gid >> 3) & 3, o = (gid >> 5) & 255;
        int g = (gid >> 13) & 1, t = gid >> 14;
        int q = slot ^ ((o >> 1) & 3);
        int k = t * 32 + q * 8 + e;
        float v = 0.f;
        if (k < 300) v = g ? Wox[o * 300 + k] : Wcx[o * 300 + k];
        WbL[gid] = f2bf(v);
    }
    if (gid < 1024) bp2[gid] = bl[gid] + br[gid];
    if (gid < 512) {
        int g = gid >> 8, o = gid & 255;
        bpL[gid] = g ? box[o] : bcx[o];
    }
    for (int i = gid; i < 65536 * 80; i += 262144) {
        int row = i / 80;
        int k = (i - row * 80) * 4;
        float4 v = make_float4(0.f, 0.f, 0.f, 0.f);
        if (k < 300) v = *(const float4*)(embs + (size_t)row * 300 + k);
        ushort4 o4;
        o4.x = f2bf(v.x); o4.y = f2bf(v.y); o4.z = f2bf(v.z); o4.w = f2bf(v.w);
        *(ushort4*)(embsB + (size_t)row * 320 + k) = o4;
    }
}

// ---------------- v10 big-level GEMM (proven), c in fp16 ----------------
// block 128 rows x (128/NG) o-cols x NG gates, 4 waves, wave 64r x 64G.

template<int NG, int HALVES, int MODE>
__global__ __launch_bounds__(256, 4)
void mfma_gemm(const ushort* __restrict__ A,
               const ushort* __restrict__ Wb,
               const float* __restrict__ bp,
               const __half* __restrict__ Cprev,
               __half* __restrict__ c_out,
               ushort* __restrict__ h_out,
               float* __restrict__ fout,     // MODE 2: fp32 [c(64,256); h(64,256)]
               int M)
{
    constexpr int K = HALVES * 32;
    constexpr int OW = 128 / NG;
    __shared__ __align__(16) ushort As[2][512 * 8];
    __shared__ __align__(16) ushort Bs[2][512 * 8];

    const int tid = threadIdx.x;
    const int wid = tid >> 6, ln = tid & 63;
    const int lq = ln >> 4, lr = ln & 15;
    const int wm = wid >> 1, wn = wid & 1;
    const int rowBlk = blockIdx.x * 128;
    const int o0 = blockIdx.y * OW;

    f32x4 acc[4][4];
#pragma unroll
    for (int m = 0; m < 4; ++m)
#pragma unroll
        for (int f = 0; f < 4; ++f) acc[m][f] = f32x4{0.f, 0.f, 0.f, 0.f};

    const int ar0 = tid >> 2,  as0 = tid & 3;
    const int ar1 = ar0 + 64;
    const int aq0 = (as0 - ((ar0 >> 1) & 3)) & 3;
    const int aq1 = (as0 - ((ar1 >> 1) & 3)) & 3;
    const ushort* aP0 = A + (size_t)min(rowBlk + ar0, M - 1) * K + aq0 * 8;
    const ushort* aP1 = A + (size_t)min(rowBlk + ar1, M - 1) * K + aq1 * 8;
    const int bj0 = tid >> 2,        bs0 = tid & 3;
    const int bj1 = (tid + 256) >> 2;
    const int bg0 = bj0 / OW, bo0 = o0 + (bj0 & (OW - 1));
    const int bg1 = bj1 / OW, bo1 = o0 + (bj1 & (OW - 1));
    const ushort* bP0 = Wb + ((size_t)bg0 * 1024 + bo0 * 4 + bs0) * 8;
    const ushort* bP1 = Wb + ((size_t)bg1 * 1024 + bo1 * 4 + bs0) * 8;
    constexpr size_t BSTR = (size_t)NG * 1024 * 8;

    const int aSw = (lq + ((lr >> 1) & 3)) & 3;
    const int bSw = lq ^ ((lr >> 1) & 3);
    int aOff[4];
#pragma unroll
    for (int m = 0; m < 4; ++m)
        aOff[m] = ((wm * 64 + m * 16 + lr) * 4 + aSw) * 8;
    int bOff[4];
#pragma unroll
    for (int f = 0; f < 4; ++f)
        bOff[f] = ((f * 32 + wn * 16 + lr) * 4 + bSw) * 8;

    gld_lds16(aP0, &As[0][tid * 8]);
    gld_lds16(aP1, &As[0][(tid + 256) * 8]);
    gld_lds16(bP0, &Bs[0][tid * 8]);
    gld_lds16(bP1, &Bs[0][(tid + 256) * 8]);

#pragma unroll
    for (int h = 0; h < HALVES; ++h) {
        __syncthreads();
        const int cur = h & 1;
        if (h + 1 < HALVES) {
            gld_lds16(aP0 + (size_t)(h + 1) * 32, &As[cur ^ 1][tid * 8]);
            gld_lds16(aP1 + (size_t)(h + 1) * 32, &As[cur ^ 1][(tid + 256) * 8]);
            gld_lds16(bP0 + (size_t)(h + 1) * BSTR, &Bs[cur ^ 1][tid * 8]);
            gld_lds16(bP1 + (size_t)(h + 1) * BSTR, &Bs[cur ^ 1][(tid + 256) * 8]);
        }
        bf16x8 a[4];
#pragma unroll
        for (int m = 0; m < 4; ++m)
            a[m] = *(const bf16x8*)&As[cur][aOff[m]];
#pragma unroll
        for (int f = 0; f < 4; ++f) {
            bf16x8 b = *(const bf16x8*)&Bs[cur][bOff[f]];
#pragma unroll
            for (int m = 0; m < 4; ++m)
                acc[m][f] = __builtin_amdgcn_mfma_f32_16x16x32_bf16(a[m], b, acc[m][f], 0, 0, 0);
        }
    }

#pragma unroll
    for (int m = 0; m < 4; ++m) {
        const int row0 = rowBlk + wm * 64 + m * 16 + lq * 4;
        if constexpr (MODE == 0) {
#pragma unroll
            for (int ob = 0; ob < 2; ++ob) {
                const int col = o0 + ob * 32 + wn * 16 + lr;
                const float bc = bp[col], bo = bp[256 + col];
#pragma unroll
                for (int j = 0; j < 4; ++j) {
                    int row = row0 + j;
                    if (row < M) {
                        float cv = acc[m][ob][j] + bc;
                        float ov = acc[m][2 + ob][j] + bo;
                        c_out[(size_t)row * 256 + col] = __float2half(cv);
                        h_out[(size_t)row * 256 + col] = f2bf(fsig(ov) * ftanh(cv));
                    }
                }
            }
        } else {
            const int col = o0 + wn * 16 + lr;
            const float bi  = bp[col],       blf = bp[256 + col];
            const float brf = bp[512 + col], bu  = bp[768 + col];
#pragma unroll
            for (int j = 0; j < 4; ++j) {
                int row = row0 + j;
                if (row < M) {
                    float gi = fsig(acc[m][0][j] + bi);
                    float lf = fsig(acc[m][1][j] + blf);
                    float rf = fsig(acc[m][2][j] + brf);
                    float gu = ftanh(acc[m][3][j] + bu);
                    float lc = __half2float(Cprev[(size_t)row * 512 + col]);
                    float rc = __half2float(Cprev[(size_t)row * 512 + 256 + col]);
                    float cv = gi * gu + lf * lc + rf * rc;
                    float hv = ftanh(cv);
                    if constexpr (MODE == 2) {
                        fout[(size_t)row * 256 + col] = cv;
                        fout[16384 + (size_t)row * 256 + col] = hv;
                    } else {
                        c_out[(size_t)row * 256 + col] = __float2half(cv);
                        h_out[(size_t)row * 256 + col] = f2bf(hv);
                    }
                }
            }
        }
    }
}

// ---------------- host ----------------

extern "C" void kernel_launch(void* const* d_in, const int* in_sizes, int n_in,
                              void* d_out, int out_size, void* d_ws, size_t ws_size,
                              hipStream_t stream)
{
    const float* embs = (const float*)d_in[0];
    const float* Wcx  = (const float*)d_in[1];
    const float* bcx  = (const float*)d_in[2];
    const float* Wox  = (const float*)d_in[3];
    const float* box  = (const float*)d_in[4];
    const float* Wl   = (const float*)d_in[5];
    const float* bl   = (const float*)d_in[6];
    const float* Wr   = (const float*)d_in[7];
    const float* br   = (const float*)d_in[8];

    char* p = (char*)d_ws;
    ushort* Wb2 = (ushort*)p;  p += (size_t)524288 * 2;
    ushort* WbL = (ushort*)p;  p += (size_t)163840 * 2;
    float*  bp2 = (float*)p;   p += 1024 * 4;
    float*  bpL = (float*)p;   p += 512 * 4;
    __half* c0  = (__half*)p;  p += (size_t)65536 * 256 * 2;   // 32 MB
    ushort* h0  = (ushort*)p;  p += (size_t)65536 * 256 * 2;   // 32 MB
    char* X = p;
    ushort* embsB = (ushort*)X;                                 // 40 MB (dead after leaf)
    __half* cA = (__half*)X;                                    // 16 MB (32768,256)
    ushort* hA = (ushort*)(X + (size_t)16 * 1024 * 1024);       // 16 MB
    __half* cB = (__half*)(X + (size_t)32 * 1024 * 1024);       //  8 MB (16384,256)
    ushort* hB = (ushort*)(X + (size_t)40 * 1024 * 1024);       //  8 MB

    prep<<<1024, 256, 0, stream>>>(Wl, Wr, bl, br, Wcx, Wox, bcx, box, embs,
                                   Wb2, WbL, bp2, bpL, embsB);

    // leaf: (65536,320) @ (320, 2*256) -> c0 fp16, h0 bf16
    mfma_gemm<2, 10, 0><<<dim3(512, 4), 256, 0, stream>>>(
        embsB, WbL, bpL, nullptr, c0, h0, nullptr, 65536);

    // tree levels: out-np 512..2 via MODE 1, np=1 via MODE 2 -> dout
    const ushort* hin = h0;
    const __half* cin = c0;
    __half* cping[2] = {cA, cB};
    ushort* hping[2] = {hA, hB};
    int flip = 0;
    for (int np = 512; np >= 1; np >>= 1) {
        int M = 64 * np;
        int gx = (M + 127) / 128;
        if (np == 1) {
            mfma_gemm<4, 16, 2><<<dim3(gx, 8), 256, 0, stream>>>(
                hin, Wb2, bp2, cin, nullptr, nullptr, (float*)d_out, M);
        } else {
            __half* co = cping[flip]; ushort* ho = hping[flip];
            mfma_gemm<4, 16, 1><<<dim3(gx, 8), 256, 0, stream>>>(
                hin, Wb2, bp2, cin, co, ho, nullptr, M);
            cin = co; hin = ho; flip ^= 1;
        }
    }
}